// Round 9
// baseline (246.534 us; speedup 1.0000x reference)
//
#include <hip/hip_runtime.h>
#include <hip/hip_bf16.h>

#define NROWS  8192
#define DIM    256
#define MARGIN 0.3f

using bf16x8 = __attribute__((ext_vector_type(8))) short;
using f32x4  = __attribute__((ext_vector_type(4))) float;

__device__ inline ushort f2bf(float f) {
    __hip_bfloat16 h = __float2bfloat16(f);
    return *reinterpret_cast<ushort*>(&h);
}
__device__ inline float bf2f(ushort u) {
    return __uint_as_float(((unsigned)u) << 16);
}
// Order-preserving float<->uint transform: bitwise atomicMax/Min == float max/min.
__device__ inline unsigned f2ord(float f) {
    unsigned b = __float_as_uint(f);
    return (b & 0x80000000u) ? ~b : (b | 0x80000000u);
}
__device__ inline float ord2f(unsigned u) {
    return __uint_as_float((u & 0x80000000u) ? (u & 0x7FFFFFFFu) : ~u);
}
// Async global->LDS, 16B per lane. LDS dest is wave-uniform base + lane*16.
__device__ inline void ld16_g2l(const void* g, void* l) {
    __builtin_amdgcn_global_load_lds(
        (const __attribute__((address_space(1))) unsigned int*)g,
        (__attribute__((address_space(3))) unsigned int*)l, 16, 0, 0);
}

// ---- workspace layout (bytes) ----
#define XBS_OFF 0u            // 8192*256*2 = 4194304  normalized bf16 rows (input order)
#define SQS_OFF 4194304u      // 32768  ||x||^2 per row
#define PMX_OFF 4259840u      // 32768  ordered-uint max over positives of d^2
#define NMN_OFF 4292608u      // 32768  ordered-uint min over negatives of d^2
#define ACC_OFF 4327424u      // 8      double loss accumulator
#define TIK_OFF 4327432u      // 4      finalize completion ticket

// K1: one wave per row. Normalize fp32 -> bf16 in place. Block 0 thread 0
// zeroes the finalize accumulator+ticket (stream-order visible, no fences).
__global__ __launch_bounds__(256) void norm_kernel(
    const float* __restrict__ in, ushort* __restrict__ xbs,
    float* __restrict__ sqs, unsigned* __restrict__ pmax,
    unsigned* __restrict__ nmin, double* __restrict__ accd,
    unsigned* __restrict__ ticket)
{
    int row  = blockIdx.x * 4 + (threadIdx.x >> 6);
    int lane = threadIdx.x & 63;
    if (blockIdx.x == 0 && threadIdx.x == 0) { *accd = 0.0; *ticket = 0u; }
    float4 v = ((const float4*)(in + (size_t)row * DIM))[lane];
    float ss = v.x * v.x + v.y * v.y + v.z * v.z + v.w * v.w;
#pragma unroll
    for (int m = 1; m < 64; m <<= 1) ss += __shfl_xor(ss, m, 64);
    float inv = 1.0f / (sqrtf(ss) + 1e-12f);

    ushort4 st;
    st.x = f2bf(v.x * inv); st.y = f2bf(v.y * inv);
    st.z = f2bf(v.z * inv); st.w = f2bf(v.w * inv);

    ((ushort4*)(xbs + (size_t)row * DIM))[lane] = st;

    float a0 = bf2f(st.x), a1 = bf2f(st.y), a2 = bf2f(st.z), a3 = bf2f(st.w);
    float s2 = a0 * a0 + a1 * a1 + a2 * a2 + a3 * a3;
#pragma unroll
    for (int m = 1; m < 64; m <<= 1) s2 += __shfl_xor(s2, m, 64);
    if (lane == 0) {
        sqs[row]  = s2;
        pmax[row] = 0x007FFFFFu;  // f2ord(-inf)
        nmin[row] = 0xFF800000u;  // f2ord(+inf)
    }
}

// K2: SYMMETRIC-HALF gram + hard-pos/hard-neg. d^2 is symmetric and the
// min/max reductions are idempotent, so only the lower-triangle blocks
// (c <= r over 32x32 blocks of 256 rows x 256 cols; 528 of 1024) are
// computed — 51.5% of R7's MFMA/LDS/staging work. Each block updates BOTH
// its row range (register pm/nm + end atomics, as R7) and its column range
// (per-tile col min/max -> cross-quad shfl -> LDS atomic accumulators ->
// one global atomic pair per column at block end). Coverage: pair (i,j) with
// b(j)<=b(i) is seen row-side in block (b(i),b(j)); otherwise column-side in
// block (b(j),b(i)). Double visits are harmless (max/min idempotent).
// Tiles now compute the full w = sq_i + sq_j - 2 dot (per-lane sqa4 hoisted)
// so one value serves both sides; finalize drops its +sqs.
// Inner staging structure (shared LDS double buffer, XOR-swizzle pair,
// prefetch-at-top, per-stage __syncthreads) is byte-identical to R0/R7;
// R8 proved counted-vmcnt is null here, so it is reverted.
__global__ __launch_bounds__(256, 2) void gram_kernel(
    const ushort* __restrict__ xbs, const float* __restrict__ sqs,
    const int* __restrict__ tgt, unsigned* __restrict__ pmax,
    unsigned* __restrict__ nmin)
{
    __shared__ struct {
        char  buf[2][16384];   // B stage buffers: 32 cols x 512B, swizzled
        float sqc[256];        // per-col ||x||^2 for this 256-col chunk
        int   tgc[256];        // per-col class
        int   tga[256];        // per-row class for this block's 256 rows
        unsigned colp[256];    // col-side hard-pos accumulator (ordered uint)
        unsigned coln[256];    // col-side hard-neg accumulator
    } sm;

    const int wave = threadIdx.x >> 6;
    const int lane = threadIdx.x & 63;
    const int l15  = lane & 15;
    const int quad = lane >> 4;

    // Lower-triangle block mapping: id -> (rb, cb), cb <= rb, rb in [0,32).
    // cum(rb) = rb(rb+1)/2; float sqrt + integer fix-up (robust to fp error).
    const int id = blockIdx.x;
    int rb = (int)((sqrtf(8.0f * (float)id + 1.0f) - 1.0f) * 0.5f);
    while ((rb + 1) * (rb + 2) / 2 <= id) ++rb;
    while (rb * (rb + 1) / 2 > id) --rb;
    const int cb = id - rb * (rb + 1) / 2;

    const int mbase = rb * 256 + wave * 64;
    const int nbase = cb * 256;

    // Stage per-chunk metadata into LDS + init column accumulators (once).
    {
        int c = threadIdx.x;
        sm.sqc[c]  = sqs[nbase + c];
        sm.tgc[c]  = tgt[nbase + c];
        sm.tga[c]  = tgt[rb * 256 + c];
        sm.colp[c] = 0x007FFFFFu;  // f2ord(-inf)
        sm.coln[c] = 0xFF800000u;  // f2ord(+inf)
    }

    // Preload A fragments: 4 tiles x full K=256.
    bf16x8 afrag[4][8];
#pragma unroll
    for (int a = 0; a < 4; ++a) {
        const ushort* arow = xbs + (size_t)(mbase + a * 16 + l15) * DIM + quad * 8;
#pragma unroll
        for (int kk = 0; kk < 8; ++kk)
            afrag[a][kk] = *(const bf16x8*)(arow + kk * 32);
    }
    // Per-lane ||x||^2 of this lane's 16 rows (16B-aligned float4 loads).
    f32x4 sqa4[4];
#pragma unroll
    for (int a = 0; a < 4; ++a)
        sqa4[a] = *(const f32x4*)(sqs + mbase + a * 16 + quad * 4);

    // Per-lane global source offsets for staging (xor-swizzle compensation).
    // Stage instr i writes LDS [i*1024,(i+1)*1024): col=2i+(lane>>5), slot=lane&31,
    // which must hold logical chunk c = slot ^ (col&7).
    const int colh = lane >> 5, c31 = lane & 31;
    int offs[4];
#pragma unroll
    for (int j = 0; j < 4; ++j)
        offs[j] = colh * 512 + ((c31 ^ ((2 * j + colh) & 7)) << 4);

    const char* xbs_b = (const char*)xbs;

    // Prologue: issue stage 0.
    {
        const char* gbase = xbs_b + (size_t)nbase * 512;
#pragma unroll
        for (int j = 0; j < 4; ++j) {
            int i = wave * 4 + j;
            ld16_g2l(gbase + i * 1024 + offs[j], sm.buf[0] + i * 1024);
        }
    }
    __syncthreads();  // drains prologue DMA + metadata writes

    float pm[16], nm[16];
#pragma unroll
    for (int j = 0; j < 16; ++j) { pm[j] = -__builtin_inff(); nm[j] = __builtin_inff(); }

#pragma unroll 2
    for (int s = 0; s < 8; ++s) {
        // Issue stage s+1 into the other buffer (free: everyone done reading it).
        if (s < 7) {
            const char* gbase = xbs_b + (size_t)(nbase + (s + 1) * 32) * 512;
            char* lbase = sm.buf[(s + 1) & 1];
#pragma unroll
            for (int j = 0; j < 4; ++j) {
                int i = wave * 4 + j;
                ld16_g2l(gbase + i * 1024 + offs[j], lbase + i * 1024);
            }
        }
        // Compute the two 16-col tiles of the current buffer.
        const char* bufc = sm.buf[s & 1];
#pragma unroll
        for (int u = 0; u < 2; ++u) {
            const int t16 = s * 32 + u * 16;
            bf16x8 bfrag[8];
#pragma unroll
            for (int kk = 0; kk < 8; ++kk)
                bfrag[kk] = *(const bf16x8*)(bufc + u * 8192 + l15 * 512 +
                                             (((quad + 4 * kk) ^ (l15 & 7)) << 4));
            f32x4 acc4[4];
#pragma unroll
            for (int a = 0; a < 4; ++a) {
                f32x4 acc = {0.f, 0.f, 0.f, 0.f};
#pragma unroll
                for (int kk = 0; kk < 8; ++kk)
                    acc = __builtin_amdgcn_mfma_f32_16x16x32_bf16(afrag[a][kk], bfrag[kk], acc, 0, 0, 0);
                acc4[a] = acc;
            }
            const float sqc = sm.sqc[t16 + l15];
            const int   tc  = sm.tgc[t16 + l15];
            float cp = -__builtin_inff(), cn = __builtin_inff();
#pragma unroll
            for (int a = 0; a < 4; ++a)
#pragma unroll
                for (int i = 0; i < 4; ++i) {
                    const float w = fmaf(acc4[a][i], -2.0f, sqa4[a][i] + sqc);
                    const bool same = (sm.tga[wave * 64 + a * 16 + quad * 4 + i] == tc);
                    const float wp = same ? w : -__builtin_inff();
                    const float wn = same ? __builtin_inff() : w;
                    pm[a * 4 + i] = fmaxf(pm[a * 4 + i], wp);
                    nm[a * 4 + i] = fminf(nm[a * 4 + i], wn);
                    cp = fmaxf(cp, wp);
                    cn = fminf(cn, wn);
                }
            // Column side: reduce over this wave's 64 rows (4 quads hold the
            // same column set), then LDS-atomic into the block accumulators.
            cp = fmaxf(cp, __shfl_xor(cp, 16, 64));
            cp = fmaxf(cp, __shfl_xor(cp, 32, 64));
            cn = fminf(cn, __shfl_xor(cn, 16, 64));
            cn = fminf(cn, __shfl_xor(cn, 32, 64));
            if (quad == 0) {
                atomicMax(&sm.colp[t16 + l15], f2ord(cp));
                atomicMin(&sm.coln[t16 + l15], f2ord(cn));
            }
        }
        __syncthreads();  // stage-s+1 DMA landed long ago -> drain is ~free
    }

    // Row side: reduce across the 16 column-lanes (same quad), one atomic/row.
#pragma unroll
    for (int m = 1; m < 16; m <<= 1) {
#pragma unroll
        for (int j = 0; j < 16; ++j) {
            pm[j] = fmaxf(pm[j], __shfl_xor(pm[j], m, 64));
            nm[j] = fminf(nm[j], __shfl_xor(nm[j], m, 64));
        }
    }
    if (l15 == 0) {
#pragma unroll
        for (int a = 0; a < 4; ++a)
#pragma unroll
            for (int i = 0; i < 4; ++i) {
                int r = mbase + a * 16 + quad * 4 + i;
                atomicMax(&pmax[r], f2ord(pm[a * 4 + i]));
                atomicMin(&nmin[r], f2ord(nm[a * 4 + i]));
            }
    }
    // Column side: flush block accumulators (last-stage barrier ordered the
    // LDS atomics; one global atomic pair per column).
    atomicMax(&pmax[nbase + threadIdx.x], sm.colp[threadIdx.x]);
    atomicMin(&nmin[nbase + threadIdx.x], sm.coln[threadIdx.x]);
}

// K3: multi-block finalize. pmax/nmin now hold full d^2 (sq_i+sq_j-2dot), so
// no +sqs here. Self-pair is included as a "positive" (w_self ~ 0; only wins
// for singleton classes, where ap ~ 0 matches the reference fallback).
__global__ __launch_bounds__(256) void finalize_kernel(
    const unsigned* __restrict__ pmax, const unsigned* __restrict__ nmin,
    double* __restrict__ accd, unsigned* __restrict__ ticket,
    float* __restrict__ out)
{
    int r = blockIdx.x * 256 + threadIdx.x;
    float pe = ord2f(pmax[r]);
    float ne = ord2f(nmin[r]);
    float ap = sqrtf(fmaxf(pe, 0.0f));
    float an = (ne > 1e30f) ? (MARGIN + 1.0f) : sqrtf(fmaxf(ne, 0.0f));
    float h  = fmaxf(ap - an + MARGIN, 0.0f);
    double s = (double)h;
#pragma unroll
    for (int m = 1; m < 64; m <<= 1) s += __shfl_xor(s, m, 64);
    __shared__ double sh[4];
    if ((threadIdx.x & 63) == 0) sh[threadIdx.x >> 6] = s;
    __syncthreads();
    if (threadIdx.x == 0) {
        double b = sh[0] + sh[1] + sh[2] + sh[3];
        atomicAdd(accd, b);
        __threadfence();
        unsigned old = atomicAdd(ticket, 1u);
        if (old == gridDim.x - 1) {
            double total = atomicAdd(accd, 0.0);  // coherent read
            out[0] = (float)(total / (double)NROWS);
        }
    }
}

extern "C" void kernel_launch(void* const* d_in, const int* in_sizes, int n_in,
                              void* d_out, int out_size, void* d_ws, size_t ws_size,
                              hipStream_t stream) {
    const float* in  = (const float*)d_in[0];
    const int*   tgt = (const int*)d_in[1];
    float*       out = (float*)d_out;

    char* ws = (char*)d_ws;
    ushort*   xbs    = (ushort*)(ws + XBS_OFF);
    float*    sqs    = (float*)(ws + SQS_OFF);
    unsigned* pmax   = (unsigned*)(ws + PMX_OFF);
    unsigned* nmin   = (unsigned*)(ws + NMN_OFF);
    double*   accd   = (double*)(ws + ACC_OFF);
    unsigned* ticket = (unsigned*)(ws + TIK_OFF);

    norm_kernel<<<NROWS / 4, 256, 0, stream>>>(in, xbs, sqs, pmax, nmin, accd, ticket);
    gram_kernel<<<528, 256, 0, stream>>>(xbs, sqs, tgt, pmax, nmin);
    finalize_kernel<<<32, 256, 0, stream>>>(pmax, nmin, accd, ticket, out);
}

// Round 10
// 244.263 us; speedup vs baseline: 1.0093x; 1.0093x over previous
//
#include <hip/hip_runtime.h>
#include <hip/hip_bf16.h>

#define NROWS  8192
#define DIM    256
#define MARGIN 0.3f

using bf16x8 = __attribute__((ext_vector_type(8))) short;
using f32x4  = __attribute__((ext_vector_type(4))) float;

__device__ inline ushort f2bf(float f) {
    __hip_bfloat16 h = __float2bfloat16(f);
    return *reinterpret_cast<ushort*>(&h);
}
__device__ inline float bf2f(ushort u) {
    return __uint_as_float(((unsigned)u) << 16);
}
// Order-preserving float<->uint transform: bitwise atomicMax/Min == float max/min.
__device__ inline unsigned f2ord(float f) {
    unsigned b = __float_as_uint(f);
    return (b & 0x80000000u) ? ~b : (b | 0x80000000u);
}
__device__ inline float ord2f(unsigned u) {
    return __uint_as_float((u & 0x80000000u) ? (u & 0x7FFFFFFFu) : ~u);
}
// Async global->LDS, 16B per lane. LDS dest is wave-uniform base + lane*16.
__device__ inline void ld16_g2l(const void* g, void* l) {
    __builtin_amdgcn_global_load_lds(
        (const __attribute__((address_space(1))) unsigned int*)g,
        (__attribute__((address_space(3))) unsigned int*)l, 16, 0, 0);
}

// ---- workspace layout (bytes) ----
#define XBS_OFF 0u            // 8192*256*2 = 4194304  normalized bf16 rows (input order)
#define SQS_OFF 4194304u      // 32768  ||x||^2 per row
#define PMX_OFF 4259840u      // 32768  ordered-uint max over positives of d^2
#define NMN_OFF 4292608u      // 32768  ordered-uint min over negatives of d^2
#define ACC_OFF 4327424u      // 8      double loss accumulator
#define TIK_OFF 4327432u      // 4      finalize completion ticket

// K1: one wave per row. Normalize fp32 -> bf16 in place. Block 0 thread 0
// zeroes the finalize accumulator+ticket (stream-order visible, no fences).
__global__ __launch_bounds__(256) void norm_kernel(
    const float* __restrict__ in, ushort* __restrict__ xbs,
    float* __restrict__ sqs, unsigned* __restrict__ pmax,
    unsigned* __restrict__ nmin, double* __restrict__ accd,
    unsigned* __restrict__ ticket)
{
    int row  = blockIdx.x * 4 + (threadIdx.x >> 6);
    int lane = threadIdx.x & 63;
    if (blockIdx.x == 0 && threadIdx.x == 0) { *accd = 0.0; *ticket = 0u; }
    float4 v = ((const float4*)(in + (size_t)row * DIM))[lane];
    float ss = v.x * v.x + v.y * v.y + v.z * v.z + v.w * v.w;
#pragma unroll
    for (int m = 1; m < 64; m <<= 1) ss += __shfl_xor(ss, m, 64);
    float inv = 1.0f / (sqrtf(ss) + 1e-12f);

    ushort4 st;
    st.x = f2bf(v.x * inv); st.y = f2bf(v.y * inv);
    st.z = f2bf(v.z * inv); st.w = f2bf(v.w * inv);

    ((ushort4*)(xbs + (size_t)row * DIM))[lane] = st;

    float a0 = bf2f(st.x), a1 = bf2f(st.y), a2 = bf2f(st.z), a3 = bf2f(st.w);
    float s2 = a0 * a0 + a1 * a1 + a2 * a2 + a3 * a3;
#pragma unroll
    for (int m = 1; m < 64; m <<= 1) s2 += __shfl_xor(s2, m, 64);
    if (lane == 0) {
        sqs[row]  = s2;
        pmax[row] = 0x007FFFFFu;  // f2ord(-inf)
        nmin[row] = 0xFF800000u;  // f2ord(+inf)
    }
}

// K2: SYMMETRIC-HALF gram, R7-geometry-preserving. Same dim3(32,16) grid,
// same dispatch order, same 256x512 block, byte-identical staging inner loop
// (R9 proved the triangular remap destroys dispatch-order L2 locality:
// FETCH 19->282MB). Upper-triangle blocks (bx < 2*by) exit immediately ->
// 272/512 live blocks = 53% of the MFMA/LDS/staging work.
// Coverage: pair (i,j), i>j: floor(j/512)*2 <= floor(i/256) always, so (i,j)
// lies in a live block; the i<j orientation is recovered COLUMN-side:
// per-tile col min/max -> 2 cross-quad shuffles -> LDS accumulators -> one
// global atomic pair per col at block end (same per-address atomic rate R7
// sustained at 8MB WRITE). Double visits harmless (max/min idempotent).
// Tiles compute full w = sq_r + sq_c - 2 dot; finalize drops its +sqs
// (math verified absmax=0 in R9).
__global__ __launch_bounds__(256, 2) void gram_kernel(
    const ushort* __restrict__ xbs, const float* __restrict__ sqs,
    const int* __restrict__ tgt, unsigned* __restrict__ pmax,
    unsigned* __restrict__ nmin)
{
    __shared__ struct {
        char  buf[2][16384];   // B stage buffers: 32 cols x 512B, swizzled
        float sqc[512];        // per-col ||x||^2 for this 512-col chunk
        int   tgc[512];        // per-col class
        int   tga[256];        // per-row class for this block's 256 rows
        unsigned colp[512];    // col-side hard-pos accumulator (ordered uint)
        unsigned coln[512];    // col-side hard-neg accumulator
    } sm;

    const int bx = blockIdx.x, by = blockIdx.y;
    if (bx < 2 * by) return;   // upper-triangle: covered by transpose block

    const int wave = threadIdx.x >> 6;
    const int lane = threadIdx.x & 63;
    const int l15  = lane & 15;
    const int quad = lane >> 4;
    const int mbase = bx * 256 + wave * 64;
    const int nbase = by * 512;

    // Stage per-chunk metadata into LDS + init col accumulators (once).
    {
        int c = threadIdx.x * 2;
        sm.sqc[c]     = sqs[nbase + c];
        sm.sqc[c + 1] = sqs[nbase + c + 1];
        sm.tgc[c]     = tgt[nbase + c];
        sm.tgc[c + 1] = tgt[nbase + c + 1];
        sm.tga[threadIdx.x] = tgt[bx * 256 + threadIdx.x];
        sm.colp[c] = 0x007FFFFFu; sm.colp[c + 1] = 0x007FFFFFu;  // f2ord(-inf)
        sm.coln[c] = 0xFF800000u; sm.coln[c + 1] = 0xFF800000u;  // f2ord(+inf)
    }

    // Preload A fragments: 4 tiles x full K=256.
    bf16x8 afrag[4][8];
#pragma unroll
    for (int a = 0; a < 4; ++a) {
        const ushort* arow = xbs + (size_t)(mbase + a * 16 + l15) * DIM + quad * 8;
#pragma unroll
        for (int kk = 0; kk < 8; ++kk)
            afrag[a][kk] = *(const bf16x8*)(arow + kk * 32);
    }
    // Per-lane ||x||^2 of this lane's 16 rows.
    f32x4 sqa4[4];
#pragma unroll
    for (int a = 0; a < 4; ++a)
        sqa4[a] = *(const f32x4*)(sqs + mbase + a * 16 + quad * 4);

    // Per-lane global source offsets for staging (xor-swizzle compensation).
    // Stage instr i writes LDS [i*1024,(i+1)*1024): col=2i+(lane>>5), slot=lane&31,
    // which must hold logical chunk c = slot ^ (col&7).
    const int colh = lane >> 5, c31 = lane & 31;
    int offs[4];
#pragma unroll
    for (int j = 0; j < 4; ++j)
        offs[j] = colh * 512 + ((c31 ^ ((2 * j + colh) & 7)) << 4);

    const char* xbs_b = (const char*)xbs;

    // Prologue: issue stage 0.
    {
        const char* gbase = xbs_b + (size_t)nbase * 512;
#pragma unroll
        for (int j = 0; j < 4; ++j) {
            int i = wave * 4 + j;
            ld16_g2l(gbase + i * 1024 + offs[j], sm.buf[0] + i * 1024);
        }
    }
    __syncthreads();  // drains prologue DMA + metadata writes

    float pm[16], nm[16];
#pragma unroll
    for (int j = 0; j < 16; ++j) { pm[j] = -__builtin_inff(); nm[j] = __builtin_inff(); }

#pragma unroll 2
    for (int s = 0; s < 16; ++s) {
        // Issue stage s+1 into the other buffer (free: everyone done reading it).
        if (s < 15) {
            const char* gbase = xbs_b + (size_t)(nbase + (s + 1) * 32) * 512;
            char* lbase = sm.buf[(s + 1) & 1];
#pragma unroll
            for (int j = 0; j < 4; ++j) {
                int i = wave * 4 + j;
                ld16_g2l(gbase + i * 1024 + offs[j], lbase + i * 1024);
            }
        }
        // Compute the two 16-col tiles of the current buffer.
        const char* bufc = sm.buf[s & 1];
#pragma unroll
        for (int u = 0; u < 2; ++u) {
            const int t16 = s * 32 + u * 16;
            bf16x8 bfrag[8];
#pragma unroll
            for (int kk = 0; kk < 8; ++kk)
                bfrag[kk] = *(const bf16x8*)(bufc + u * 8192 + l15 * 512 +
                                             (((quad + 4 * kk) ^ (l15 & 7)) << 4));
            f32x4 acc4[4];
#pragma unroll
            for (int a = 0; a < 4; ++a) {
                f32x4 acc = {0.f, 0.f, 0.f, 0.f};
#pragma unroll
                for (int kk = 0; kk < 8; ++kk)
                    acc = __builtin_amdgcn_mfma_f32_16x16x32_bf16(afrag[a][kk], bfrag[kk], acc, 0, 0, 0);
                acc4[a] = acc;
            }
            const float sqc = sm.sqc[t16 + l15];
            const int   tc  = sm.tgc[t16 + l15];
            float cp = -__builtin_inff(), cn = __builtin_inff();
#pragma unroll
            for (int a = 0; a < 4; ++a)
#pragma unroll
                for (int i = 0; i < 4; ++i) {
                    const float w = fmaf(acc4[a][i], -2.0f, sqa4[a][i] + sqc);
                    const bool same = (sm.tga[wave * 64 + a * 16 + quad * 4 + i] == tc);
                    const float wp = same ? w : -__builtin_inff();
                    const float wn = same ? __builtin_inff() : w;
                    pm[a * 4 + i] = fmaxf(pm[a * 4 + i], wp);
                    nm[a * 4 + i] = fminf(nm[a * 4 + i], wn);
                    cp = fmaxf(cp, wp);
                    cn = fminf(cn, wn);
                }
            // Column side: fold this wave's 64 rows (4 quads, same col set),
            // then LDS-atomic into the block accumulators.
            cp = fmaxf(cp, __shfl_xor(cp, 16, 64));
            cp = fmaxf(cp, __shfl_xor(cp, 32, 64));
            cn = fminf(cn, __shfl_xor(cn, 16, 64));
            cn = fminf(cn, __shfl_xor(cn, 32, 64));
            if (quad == 0) {
                atomicMax(&sm.colp[t16 + l15], f2ord(cp));
                atomicMin(&sm.coln[t16 + l15], f2ord(cn));
            }
        }
        __syncthreads();  // also orders this stage's col LDS atomics
    }

    // Row side: reduce across the 16 column-lanes (same quad), one atomic/row.
#pragma unroll
    for (int m = 1; m < 16; m <<= 1) {
#pragma unroll
        for (int j = 0; j < 16; ++j) {
            pm[j] = fmaxf(pm[j], __shfl_xor(pm[j], m, 64));
            nm[j] = fminf(nm[j], __shfl_xor(nm[j], m, 64));
        }
    }
    if (l15 == 0) {
#pragma unroll
        for (int a = 0; a < 4; ++a)
#pragma unroll
            for (int i = 0; i < 4; ++i) {
                int r = mbase + a * 16 + quad * 4 + i;
                atomicMax(&pmax[r], f2ord(pm[a * 4 + i]));
                atomicMin(&nmin[r], f2ord(nm[a * 4 + i]));
            }
    }
    // Column side: flush block accumulators (2 cols per thread).
    {
        int c0 = threadIdx.x, c1 = threadIdx.x + 256;
        atomicMax(&pmax[nbase + c0], sm.colp[c0]);
        atomicMax(&pmax[nbase + c1], sm.colp[c1]);
        atomicMin(&nmin[nbase + c0], sm.coln[c0]);
        atomicMin(&nmin[nbase + c1], sm.coln[c1]);
    }
}

// K3: multi-block finalize. pmax/nmin hold full d^2 (sq_i+sq_j-2dot), so no
// +sqs here. Self-pair is included as a "positive" (w_self ~ 0; only wins for
// singleton classes, where ap ~ 0 matches the reference fallback).
__global__ __launch_bounds__(256) void finalize_kernel(
    const unsigned* __restrict__ pmax, const unsigned* __restrict__ nmin,
    double* __restrict__ accd, unsigned* __restrict__ ticket,
    float* __restrict__ out)
{
    int r = blockIdx.x * 256 + threadIdx.x;
    float pe = ord2f(pmax[r]);
    float ne = ord2f(nmin[r]);
    float ap = sqrtf(fmaxf(pe, 0.0f));
    float an = (ne > 1e30f) ? (MARGIN + 1.0f) : sqrtf(fmaxf(ne, 0.0f));
    float h  = fmaxf(ap - an + MARGIN, 0.0f);
    double s = (double)h;
#pragma unroll
    for (int m = 1; m < 64; m <<= 1) s += __shfl_xor(s, m, 64);
    __shared__ double sh[4];
    if ((threadIdx.x & 63) == 0) sh[threadIdx.x >> 6] = s;
    __syncthreads();
    if (threadIdx.x == 0) {
        double b = sh[0] + sh[1] + sh[2] + sh[3];
        atomicAdd(accd, b);
        __threadfence();
        unsigned old = atomicAdd(ticket, 1u);
        if (old == gridDim.x - 1) {
            double total = atomicAdd(accd, 0.0);  // coherent read
            out[0] = (float)(total / (double)NROWS);
        }
    }
}

extern "C" void kernel_launch(void* const* d_in, const int* in_sizes, int n_in,
                              void* d_out, int out_size, void* d_ws, size_t ws_size,
                              hipStream_t stream) {
    const float* in  = (const float*)d_in[0];
    const int*   tgt = (const int*)d_in[1];
    float*       out = (float*)d_out;

    char* ws = (char*)d_ws;
    ushort*   xbs    = (ushort*)(ws + XBS_OFF);
    float*    sqs    = (float*)(ws + SQS_OFF);
    unsigned* pmax   = (unsigned*)(ws + PMX_OFF);
    unsigned* nmin   = (unsigned*)(ws + NMN_OFF);
    double*   accd   = (double*)(ws + ACC_OFF);
    unsigned* ticket = (unsigned*)(ws + TIK_OFF);

    norm_kernel<<<NROWS / 4, 256, 0, stream>>>(in, xbs, sqs, pmax, nmin, accd, ticket);
    gram_kernel<<<dim3(32, 16), 256, 0, stream>>>(xbs, sqs, tgt, pmax, nmin);
    finalize_kernel<<<32, 256, 0, stream>>>(pmax, nmin, accd, ticket, out);
}

// Round 11
// 107.464 us; speedup vs baseline: 2.2941x; 2.2730x over previous
//
#include <hip/hip_runtime.h>
#include <hip/hip_bf16.h>

#define NROWS  8192
#define DIM    256
#define MARGIN 0.3f

using bf16x8 = __attribute__((ext_vector_type(8))) short;
using f32x4  = __attribute__((ext_vector_type(4))) float;

__device__ inline ushort f2bf(float f) {
    __hip_bfloat16 h = __float2bfloat16(f);
    return *reinterpret_cast<ushort*>(&h);
}
__device__ inline float bf2f(ushort u) {
    return __uint_as_float(((unsigned)u) << 16);
}
// Order-preserving float<->uint transform: bitwise atomicMax/Min == float max/min.
__device__ inline unsigned f2ord(float f) {
    unsigned b = __float_as_uint(f);
    return (b & 0x80000000u) ? ~b : (b | 0x80000000u);
}
__device__ inline float ord2f(unsigned u) {
    return __uint_as_float((u & 0x80000000u) ? (u & 0x7FFFFFFFu) : ~u);
}
// Async global->LDS, 16B per lane. LDS dest is wave-uniform base + lane*16.
__device__ inline void ld16_g2l(const void* g, void* l) {
    __builtin_amdgcn_global_load_lds(
        (const __attribute__((address_space(1))) unsigned int*)g,
        (__attribute__((address_space(3))) unsigned int*)l, 16, 0, 0);
}

// ---- workspace layout (bytes) ----
#define XBS_OFF 0u            // 8192*256*2 = 4194304  normalized bf16 rows (input order)
#define SQS_OFF 4194304u      // 32768  ||x||^2 per row
#define PMX_OFF 4259840u      // 32768  ordered-uint max over positives of (sqc-2acc)
#define NMN_OFF 4292608u      // 32768  ordered-uint min over negatives
#define ACC_OFF 4327424u      // 8      double loss accumulator
#define TIK_OFF 4327432u      // 4      finalize completion ticket

// K1: one wave per row. Normalize fp32 -> bf16 IN PLACE (no sort; R7 proved
// the sort's fast-path VALU saving < its kernel+dispatch cost). Block 0
// thread 0 zeroes the finalize accumulator+ticket (stream-order visible).
__global__ __launch_bounds__(256) void norm_kernel(
    const float* __restrict__ in, ushort* __restrict__ xbs,
    float* __restrict__ sqs, unsigned* __restrict__ pmax,
    unsigned* __restrict__ nmin, double* __restrict__ accd,
    unsigned* __restrict__ ticket)
{
    int row  = blockIdx.x * 4 + (threadIdx.x >> 6);
    int lane = threadIdx.x & 63;
    if (blockIdx.x == 0 && threadIdx.x == 0) { *accd = 0.0; *ticket = 0u; }
    float4 v = ((const float4*)(in + (size_t)row * DIM))[lane];
    float ss = v.x * v.x + v.y * v.y + v.z * v.z + v.w * v.w;
#pragma unroll
    for (int m = 1; m < 64; m <<= 1) ss += __shfl_xor(ss, m, 64);
    float inv = 1.0f / (sqrtf(ss) + 1e-12f);

    ushort4 st;
    st.x = f2bf(v.x * inv); st.y = f2bf(v.y * inv);
    st.z = f2bf(v.z * inv); st.w = f2bf(v.w * inv);

    ((ushort4*)(xbs + (size_t)row * DIM))[lane] = st;

    float a0 = bf2f(st.x), a1 = bf2f(st.y), a2 = bf2f(st.z), a3 = bf2f(st.w);
    float s2 = a0 * a0 + a1 * a1 + a2 * a2 + a3 * a3;
#pragma unroll
    for (int m = 1; m < 64; m <<= 1) s2 += __shfl_xor(s2, m, 64);
    if (lane == 0) {
        sqs[row]  = s2;
        pmax[row] = 0x007FFFFFu;  // f2ord(-inf)
        nmin[row] = 0xFF800000u;  // f2ord(+inf)
    }
}

// K2: fused gram + hard-pos/hard-neg — the measured-best R7 kernel, restored
// verbatim. 4 waves, 256 rows x 512 cols per block, full sweep (symmetric-half
// variants R9/R10 both died on cross-XCD atomic coherence churn: WRITE 8->69MB,
// FETCH 19->52MB). Shared double-buffered LDS B staging, XOR-swizzle pair,
// stage-s+1 prefetch at stage-s top, per-stage __syncthreads (counted-vmcnt
// triple-buffer was null, R8). Rows unsorted; every tile runs the slow-path
// epilogue. Row-side-only atomics: each row touched by only the 16 same-bx
// blocks -> no cross-XCD ping-pong (WRITE stays 8MB).
__global__ __launch_bounds__(256, 2) void gram_kernel(
    const ushort* __restrict__ xbs, const float* __restrict__ sqs,
    const int* __restrict__ tgt, unsigned* __restrict__ pmax,
    unsigned* __restrict__ nmin)
{
    __shared__ struct {
        char  buf[2][16384];   // B stage buffers: 32 cols x 512B, swizzled
        float sqc[512];        // per-col ||x||^2 for this 512-col chunk
        int   tgc[512];        // per-col class
        int   tga[256];        // per-row class for this block's 256 rows
    } sm;

    const int wave = threadIdx.x >> 6;
    const int lane = threadIdx.x & 63;
    const int l15  = lane & 15;
    const int quad = lane >> 4;
    const int mbase = blockIdx.x * 256 + wave * 64;
    const int nbase = blockIdx.y * 512;

    // Stage per-chunk metadata into LDS (once).
    {
        int c = threadIdx.x * 2;
        sm.sqc[c]     = sqs[nbase + c];
        sm.sqc[c + 1] = sqs[nbase + c + 1];
        sm.tgc[c]     = tgt[nbase + c];
        sm.tgc[c + 1] = tgt[nbase + c + 1];
        sm.tga[threadIdx.x] = tgt[blockIdx.x * 256 + threadIdx.x];
    }

    // Preload A fragments: 4 tiles x full K=256.
    bf16x8 afrag[4][8];
#pragma unroll
    for (int a = 0; a < 4; ++a) {
        const ushort* arow = xbs + (size_t)(mbase + a * 16 + l15) * DIM + quad * 8;
#pragma unroll
        for (int kk = 0; kk < 8; ++kk)
            afrag[a][kk] = *(const bf16x8*)(arow + kk * 32);
    }

    // Per-lane global source offsets for staging (xor-swizzle compensation).
    // Stage instr i writes LDS [i*1024,(i+1)*1024): col=2i+(lane>>5), slot=lane&31,
    // which must hold logical chunk c = slot ^ (col&7).
    const int colh = lane >> 5, c31 = lane & 31;
    int offs[4];
#pragma unroll
    for (int j = 0; j < 4; ++j)
        offs[j] = colh * 512 + ((c31 ^ ((2 * j + colh) & 7)) << 4);

    const char* xbs_b = (const char*)xbs;

    // Prologue: issue stage 0.
    {
        const char* gbase = xbs_b + (size_t)nbase * 512;
#pragma unroll
        for (int j = 0; j < 4; ++j) {
            int i = wave * 4 + j;
            ld16_g2l(gbase + i * 1024 + offs[j], sm.buf[0] + i * 1024);
        }
    }
    __syncthreads();  // drains prologue DMA + metadata writes

    float pm[16], nm[16];
#pragma unroll
    for (int j = 0; j < 16; ++j) { pm[j] = -__builtin_inff(); nm[j] = __builtin_inff(); }

#pragma unroll 2
    for (int s = 0; s < 16; ++s) {
        // Issue stage s+1 into the other buffer (free: everyone done reading it).
        if (s < 15) {
            const char* gbase = xbs_b + (size_t)(nbase + (s + 1) * 32) * 512;
            char* lbase = sm.buf[(s + 1) & 1];
#pragma unroll
            for (int j = 0; j < 4; ++j) {
                int i = wave * 4 + j;
                ld16_g2l(gbase + i * 1024 + offs[j], lbase + i * 1024);
            }
        }
        // Compute the two 16-col tiles of the current buffer.
        const char* bufc = sm.buf[s & 1];
#pragma unroll
        for (int u = 0; u < 2; ++u) {
            const int t16 = s * 32 + u * 16;
            bf16x8 bfrag[8];
#pragma unroll
            for (int kk = 0; kk < 8; ++kk)
                bfrag[kk] = *(const bf16x8*)(bufc + u * 8192 + l15 * 512 +
                                             (((quad + 4 * kk) ^ (l15 & 7)) << 4));
            f32x4 acc4[4];
#pragma unroll
            for (int a = 0; a < 4; ++a) {
                f32x4 acc = {0.f, 0.f, 0.f, 0.f};
#pragma unroll
                for (int kk = 0; kk < 8; ++kk)
                    acc = __builtin_amdgcn_mfma_f32_16x16x32_bf16(afrag[a][kk], bfrag[kk], acc, 0, 0, 0);
                acc4[a] = acc;
            }
            const float sqc = sm.sqc[t16 + l15];
            const int   tc  = sm.tgc[t16 + l15];
#pragma unroll
            for (int a = 0; a < 4; ++a)
#pragma unroll
                for (int i = 0; i < 4; ++i) {
                    const float v = fmaf(acc4[a][i], -2.0f, sqc);
                    const bool same = (sm.tga[wave * 64 + a * 16 + quad * 4 + i] == tc);
                    pm[a * 4 + i] = fmaxf(pm[a * 4 + i], same ? v : -__builtin_inff());
                    nm[a * 4 + i] = fminf(nm[a * 4 + i], same ? __builtin_inff() : v);
                }
        }
        __syncthreads();  // stage-s+1 DMA landed long ago -> drain is ~free
    }

    // Reduce across the 16 column-lanes (same quad), then one atomic per row.
#pragma unroll
    for (int m = 1; m < 16; m <<= 1) {
#pragma unroll
        for (int j = 0; j < 16; ++j) {
            pm[j] = fmaxf(pm[j], __shfl_xor(pm[j], m, 64));
            nm[j] = fminf(nm[j], __shfl_xor(nm[j], m, 64));
        }
    }
    if (l15 == 0) {
#pragma unroll
        for (int a = 0; a < 4; ++a)
#pragma unroll
            for (int i = 0; i < 4; ++i) {
                int r = mbase + a * 16 + quad * 4 + i;
                atomicMax(&pmax[r], f2ord(pm[a * 4 + i]));
                atomicMin(&nmin[r], f2ord(nm[a * 4 + i]));
            }
    }
}

// K3: multi-block finalize with fp64 atomic accumulation + completion ticket
// (accd/ticket zeroed by norm_kernel). Self-pair is included as a "positive"
// (d2_self ~ 0, never wins unless the class is a singleton, where ap ~ 0
// matches the reference fallback).
__global__ __launch_bounds__(256) void finalize_kernel(
    const unsigned* __restrict__ pmax, const unsigned* __restrict__ nmin,
    const float* __restrict__ sqs, double* __restrict__ accd,
    unsigned* __restrict__ ticket, float* __restrict__ out)
{
    int r = blockIdx.x * 256 + threadIdx.x;
    float pe = ord2f(pmax[r]);
    float ne = ord2f(nmin[r]);
    float ap = sqrtf(fmaxf(sqs[r] + pe, 0.0f));
    float an = (ne > 1e30f) ? (MARGIN + 1.0f) : sqrtf(fmaxf(sqs[r] + ne, 0.0f));
    float h  = fmaxf(ap - an + MARGIN, 0.0f);
    double s = (double)h;
#pragma unroll
    for (int m = 1; m < 64; m <<= 1) s += __shfl_xor(s, m, 64);
    __shared__ double sh[4];
    if ((threadIdx.x & 63) == 0) sh[threadIdx.x >> 6] = s;
    __syncthreads();
    if (threadIdx.x == 0) {
        double b = sh[0] + sh[1] + sh[2] + sh[3];
        atomicAdd(accd, b);
        __threadfence();
        unsigned old = atomicAdd(ticket, 1u);
        if (old == gridDim.x - 1) {
            double total = atomicAdd(accd, 0.0);  // coherent read
            out[0] = (float)(total / (double)NROWS);
        }
    }
}

extern "C" void kernel_launch(void* const* d_in, const int* in_sizes, int n_in,
                              void* d_out, int out_size, void* d_ws, size_t ws_size,
                              hipStream_t stream) {
    const float* in  = (const float*)d_in[0];
    const int*   tgt = (const int*)d_in[1];
    float*       out = (float*)d_out;

    char* ws = (char*)d_ws;
    ushort*   xbs    = (ushort*)(ws + XBS_OFF);
    float*    sqs    = (float*)(ws + SQS_OFF);
    unsigned* pmax   = (unsigned*)(ws + PMX_OFF);
    unsigned* nmin   = (unsigned*)(ws + NMN_OFF);
    double*   accd   = (double*)(ws + ACC_OFF);
    unsigned* ticket = (unsigned*)(ws + TIK_OFF);

    norm_kernel<<<NROWS / 4, 256, 0, stream>>>(in, xbs, sqs, pmax, nmin, accd, ticket);
    gram_kernel<<<dim3(32, 16), 256, 0, stream>>>(xbs, sqs, tgt, pmax, nmin);
    finalize_kernel<<<32, 256, 0, stream>>>(pmax, nmin, sqs, accd, ticket, out);
}